// Round 1
// baseline (1144.726 us; speedup 1.0000x reference)
//
#include <hip/hip_runtime.h>
#include <hip/hip_fp16.h>

namespace {
constexpr int Bn = 64;
constexpr int Tn = 1024;
constexpr int Kn = 256;

typedef _Float16 half2_t __attribute__((ext_vector_type(2)));

__device__ __forceinline__ float fdot2f(half2_t a, half2_t b, float c) {
#if __has_builtin(__builtin_amdgcn_fdot2)
    return __builtin_amdgcn_fdot2(a, b, c, false);
#else
    return c + (float)a.x * (float)b.x + (float)a.y * (float)b.y;
#endif
}

__device__ __forceinline__ float wave_max(float v) {
#pragma unroll
    for (int off = 32; off >= 1; off >>= 1)
        v = fmaxf(v, __shfl_xor(v, off, 64));
    return v;
}
__device__ __forceinline__ float wave_sum(float v) {
#pragma unroll
    for (int off = 32; off >= 1; off >>= 1)
        v += __shfl_xor(v, off, 64);
    return v;
}
__device__ __forceinline__ int wave_sum_i(int v) {
#pragma unroll
    for (int off = 32; off >= 1; off >>= 1)
        v += __shfl_xor(v, off, 64);
    return v;
}

__global__ __launch_bounds__(256, 1) void crf_kernel(
    const float* __restrict__ inputs,     // (B,T,K)
    const long long* __restrict__ tags,   // (B,T)
    const int* __restrict__ mask,         // (B,T)
    const float* __restrict__ trans,      // (K,K)
    const float* __restrict__ start_t,    // (K,)
    const float* __restrict__ end_t,      // (K,)
    float* __restrict__ out)              // scalar
{
    const int b    = blockIdx.x;
    const int j    = threadIdx.x;   // 0..255 : owns output column j
    const int wid  = j >> 6;
    const int lane = j & 63;

    __shared__ __align__(16) _Float16 p_sh[Kn];
    __shared__ float sh_red[4];
    __shared__ int   sh_i[4];

    // ---- E column in registers: regE[k] = (exp(trans[2k][j]), exp(trans[2k+1][j]))
    half2_t regE[Kn / 2];
#pragma unroll
    for (int k = 0; k < Kn / 2; ++k) {
        float e0 = __expf(trans[(2 * k) * Kn + j]);
        float e1 = __expf(trans[(2 * k + 1) * Kn + j]);
        half2_t e;
        e.x = (_Float16)e0;
        e.y = (_Float16)e1;
        regE[k] = e;
    }

    // ---- sequence length for this batch
    int ls = 0;
    for (int t = j; t < Tn; t += 256) ls += (mask[b * Tn + t] > 0) ? 1 : 0;
    ls = wave_sum_i(ls);
    if (lane == 0) sh_i[wid] = ls;
    __syncthreads();
    const int len = sh_i[0] + sh_i[1] + sh_i[2] + sh_i[3];
    const int end_idx = len - 1;
    __syncthreads();

    const float end_j = end_t[j];

    // ---- alpha init (t = 0)
    float alpha = inputs[(size_t)(b * Tn) * Kn + j] + start_t[j] +
                  (end_idx == 0 ? end_j : 0.f);

    // ---- forward recursion
    for (int t = 1; t < Tn; ++t) {
        // prefetch this step's emission + mask early (hidden under reduction/dot)
        const float lg = inputs[(size_t)(b * Tn + t) * Kn + j];
        const int   mk = mask[b * Tn + t];

        // block max of alpha
        float wm = wave_max(alpha);
        if (lane == 0) sh_red[wid] = wm;
        __syncthreads();                               // SYNC_A
        const float M = fmaxf(fmaxf(sh_red[0], sh_red[1]),
                              fmaxf(sh_red[2], sh_red[3]));

        // p_i = exp(alpha_i - M), published as f16
        const float p = __expf(alpha - M);
        p_sh[j] = (_Float16)p;
        __syncthreads();                               // SYNC_B

        // acc_j = sum_i p_i * E[i][j]   (E register-resident, p LDS-broadcast)
        float acc0 = 0.f, acc1 = 0.f, acc2 = 0.f, acc3 = 0.f;
        const float4* p4 = (const float4*)p_sh;
#pragma unroll
        for (int kk = 0; kk < Kn / 8; ++kk) {
            const float4 v = p4[kk];
            const half2_t h0 = __builtin_bit_cast(half2_t, v.x);
            const half2_t h1 = __builtin_bit_cast(half2_t, v.y);
            const half2_t h2 = __builtin_bit_cast(half2_t, v.z);
            const half2_t h3 = __builtin_bit_cast(half2_t, v.w);
            acc0 = fdot2f(h0, regE[4 * kk + 0], acc0);
            acc1 = fdot2f(h1, regE[4 * kk + 1], acc1);
            acc2 = fdot2f(h2, regE[4 * kk + 2], acc2);
            acc3 = fdot2f(h3, regE[4 * kk + 3], acc3);
        }
        const float s = (acc0 + acc1) + (acc2 + acc3);

        float na = M + __logf(s) + lg + (t == end_idx ? end_j : 0.f);
        alpha = (mk > 0) ? na : alpha;
    }

    // ---- denominator = logsumexp_j(alpha)
    float wm = wave_max(alpha);
    __syncthreads();
    if (lane == 0) sh_red[wid] = wm;
    __syncthreads();
    const float Mf = fmaxf(fmaxf(sh_red[0], sh_red[1]),
                           fmaxf(sh_red[2], sh_red[3]));
    float es = wave_sum(__expf(alpha - Mf));
    __syncthreads();
    if (lane == 0) sh_red[wid] = es;
    __syncthreads();
    const float denom =
        Mf + __logf(((sh_red[0] + sh_red[1]) + (sh_red[2] + sh_red[3])));

    // ---- numerator (gather path score)
    float np = 0.f;
    for (int t = j; t < Tn; t += 256) {
        const int tg = (int)tags[b * Tn + t];
        const float e = inputs[(size_t)(b * Tn + t) * Kn + tg];
        if (t == 0) {
            np += e + start_t[tg];
        } else {
            const float mf = (float)mask[b * Tn + t];
            const int tp = (int)tags[b * Tn + t - 1];
            np += mf * (e + trans[tp * Kn + tg]);
        }
    }
    if (j == 0) np += end_t[(int)tags[b * Tn + end_idx]];
    np = wave_sum(np);
    __syncthreads();
    if (lane == 0) sh_red[wid] = np;
    __syncthreads();

    if (j == 0) {
        const float numer = (sh_red[0] + sh_red[1]) + (sh_red[2] + sh_red[3]);
        atomicAdd(out, numer - denom);
    }
}

}  // namespace

extern "C" void kernel_launch(void* const* d_in, const int* in_sizes, int n_in,
                              void* d_out, int out_size, void* d_ws, size_t ws_size,
                              hipStream_t stream) {
    const float*     inputs  = (const float*)d_in[0];
    const long long* tags    = (const long long*)d_in[1];
    const int*       mask    = (const int*)d_in[2];
    const float*     trans   = (const float*)d_in[3];
    const float*     start_t = (const float*)d_in[4];
    const float*     end_t   = (const float*)d_in[5];
    float* out = (float*)d_out;

    hipMemsetAsync(out, 0, sizeof(float), stream);
    crf_kernel<<<dim3(Bn), dim3(256), 0, stream>>>(inputs, tags, mask, trans,
                                                   start_t, end_t, out);
}

// Round 2
// 896.120 us; speedup vs baseline: 1.2774x; 1.2774x over previous
//
#include <hip/hip_runtime.h>
#include <hip/hip_fp16.h>

namespace {
constexpr int Bn = 64;
constexpr int Tn = 1024;
constexpr int Kn = 256;

typedef _Float16 half2_t __attribute__((ext_vector_type(2)));

__device__ __forceinline__ float fdot2f(half2_t a, half2_t b, float c) {
#if __has_builtin(__builtin_amdgcn_fdot2)
    return __builtin_amdgcn_fdot2(a, b, c, false);
#else
    return c + (float)a.x * (float)b.x + (float)a.y * (float)b.y;
#endif
}

// ---- DPP wave-64 reductions (gfx9 row_shr / row_bcast chain) ----
template <int C>
__device__ __forceinline__ float dppmax1(float x) {
    int o = __builtin_bit_cast(int, x);
    int y = __builtin_amdgcn_update_dpp(o, o, C, 0xF, 0xF, false);  // invalid lanes keep old
    return fmaxf(x, __builtin_bit_cast(float, y));
}
template <int C>
__device__ __forceinline__ float dppadd1(float x) {
    int y = __builtin_amdgcn_update_dpp(0, __builtin_bit_cast(int, x), C, 0xF, 0xF, true);  // invalid -> 0
    return x + __builtin_bit_cast(float, y);
}
// full-wave max, result broadcast to all lanes (via lane 63)
__device__ __forceinline__ float wave_max64(float x) {
    x = dppmax1<0x111>(x);  // row_shr:1
    x = dppmax1<0x112>(x);  // row_shr:2
    x = dppmax1<0x114>(x);  // row_shr:4
    x = dppmax1<0x118>(x);  // row_shr:8
    x = dppmax1<0x142>(x);  // row_bcast:15
    x = dppmax1<0x143>(x);  // row_bcast:31
    return __builtin_bit_cast(float,
        __builtin_amdgcn_readlane(__builtin_bit_cast(int, x), 63));
}
__device__ __forceinline__ float wave_sum64(float x) {
    x = dppadd1<0x111>(x);
    x = dppadd1<0x112>(x);
    x = dppadd1<0x114>(x);
    x = dppadd1<0x118>(x);
    x = dppadd1<0x142>(x);
    x = dppadd1<0x143>(x);
    return __builtin_bit_cast(float,
        __builtin_amdgcn_readlane(__builtin_bit_cast(int, x), 63));
}

__global__ __launch_bounds__(512) void crf_kernel(
    const float* __restrict__ inputs,     // (B,T,K)
    const long long* __restrict__ tags,   // (B,T)
    const int* __restrict__ mask,         // (B,T)
    const float* __restrict__ trans,      // (K,K)
    const float* __restrict__ start_t,    // (K,)
    const float* __restrict__ end_t,      // (K,)
    float* __restrict__ out)              // scalar
{
    const int b   = blockIdx.x;
    const int tid = threadIdx.x;
    const int w   = tid >> 6;      // wave 0..7, owns i-slice [32w, 32w+32)
    const int l   = tid & 63;
    const int ls  = l & 31;        // slot within the wave's tag range
    const bool owner = (l < 32);

    // partials padded to 9 floats/row: bank stride 9 (odd) -> conflict-free
    __shared__ float part[2][Kn][9];          // [parity][tag][wave]
    __shared__ float Mv[2][8];                // per-wave max, double-buffered
    __shared__ __align__(16) _Float16 pslice[8][32];  // wave-private p slices
    __shared__ float red[8][2];
    __shared__ float sh_np;
    __shared__ int   sh_len;

    // ---- E columns in registers: regE[g][k] = (E[i0+2k][64g+l], E[i0+2k+1][64g+l])
    const int i0 = 32 * w;
    half2_t regE[4][16];
#pragma unroll
    for (int g = 0; g < 4; ++g) {
        const int jg = 64 * g + l;
#pragma unroll
        for (int k = 0; k < 16; ++k) {
            float e0 = __expf(trans[(i0 + 2 * k) * Kn + jg]);
            float e1 = __expf(trans[(i0 + 2 * k + 1) * Kn + jg]);
            half2_t e;
            e.x = (_Float16)e0;
            e.y = (_Float16)e1;
            regE[g][k] = e;
        }
    }

    if (tid == 0) { sh_len = 0; sh_np = 0.f; }
    __syncthreads();

    // ---- sequence length
    {
        int c = 0;
        for (int t = tid; t < Tn; t += 512) c += (mask[b * Tn + t] > 0) ? 1 : 0;
        float cf = wave_sum64((float)c);
        if (l == 0) atomicAdd(&sh_len, (int)(cf + 0.5f));
    }
    __syncthreads();
    const int end_idx = sh_len - 1;

    const int   jt   = 32 * w + ls;   // this thread's tag (upper lanes mirror lower)
    const float endj = end_t[jt];

    // ---- alpha init (t = 0); upper lanes parked at -inf-ish
    float alpha = inputs[(size_t)b * Tn * Kn + jt] + start_t[jt] +
                  (end_idx == 0 ? endj : 0.f);
    if (!owner) alpha = -1e30f;

    // ---- 2-deep prefetch of emissions + mask
    float lgN  = inputs[(size_t)b * Tn * Kn + (size_t)Kn + jt];
    int   mkN  = mask[b * Tn + 1];
    float lgNN = inputs[(size_t)b * Tn * Kn + 2 * (size_t)Kn + jt];
    int   mkNN = mask[b * Tn + 2];

    // publish p (wave-private, no barrier) + partial dots -> part[nx]
    auto publish_dot = [&](float alphav, int nx) {
        const float Mw = wave_max64(alphav);
        if (owner) pslice[w][ls] = (_Float16)__expf(alphav - Mw);
        if (l == 0) Mv[nx][w] = Mw;
        // same-wave LDS RAW: DS unit is in-order per wave; pin compiler order
        __asm__ volatile("" ::: "memory");
        float acc0 = 0.f, acc1 = 0.f, acc2 = 0.f, acc3 = 0.f;
        const float4* pv = (const float4*)(&pslice[w][0]);
#pragma unroll
        for (int c = 0; c < 4; ++c) {
            const float4 v = pv[c];
            const half2_t h0 = __builtin_bit_cast(half2_t, v.x);
            const half2_t h1 = __builtin_bit_cast(half2_t, v.y);
            const half2_t h2 = __builtin_bit_cast(half2_t, v.z);
            const half2_t h3 = __builtin_bit_cast(half2_t, v.w);
            acc0 = fdot2f(h0, regE[0][4 * c + 0], acc0);
            acc0 = fdot2f(h1, regE[0][4 * c + 1], acc0);
            acc0 = fdot2f(h2, regE[0][4 * c + 2], acc0);
            acc0 = fdot2f(h3, regE[0][4 * c + 3], acc0);
            acc1 = fdot2f(h0, regE[1][4 * c + 0], acc1);
            acc1 = fdot2f(h1, regE[1][4 * c + 1], acc1);
            acc1 = fdot2f(h2, regE[1][4 * c + 2], acc1);
            acc1 = fdot2f(h3, regE[1][4 * c + 3], acc1);
            acc2 = fdot2f(h0, regE[2][4 * c + 0], acc2);
            acc2 = fdot2f(h1, regE[2][4 * c + 1], acc2);
            acc2 = fdot2f(h2, regE[2][4 * c + 2], acc2);
            acc2 = fdot2f(h3, regE[2][4 * c + 3], acc2);
            acc3 = fdot2f(h0, regE[3][4 * c + 0], acc3);
            acc3 = fdot2f(h1, regE[3][4 * c + 1], acc3);
            acc3 = fdot2f(h2, regE[3][4 * c + 2], acc3);
            acc3 = fdot2f(h3, regE[3][4 * c + 3], acc3);
        }
        part[nx][0 * 64 + l][w] = acc0;
        part[nx][1 * 64 + l][w] = acc1;
        part[nx][2 * 64 + l][w] = acc2;
        part[nx][3 * 64 + l][w] = acc3;
    };

    publish_dot(alpha, 1);   // step 0's dots -> buffer 1

    // ---- forward recursion, ONE barrier per step
    for (int t = 1; t < Tn; ++t) {
        __syncthreads();

        const float lgC = lgN;
        const int   mkC = mkN;
        lgN = lgNN;
        mkN = mkNN;
        const int tp = (t + 2 < Tn) ? (t + 2) : (Tn - 1);
        lgNN = inputs[(size_t)b * Tn * Kn + (size_t)tp * Kn + jt];
        mkNN = mask[b * Tn + tp];

        const int par = t & 1;

        float mv0 = Mv[par][0], mv1 = Mv[par][1], mv2 = Mv[par][2], mv3 = Mv[par][3];
        float mv4 = Mv[par][4], mv5 = Mv[par][5], mv6 = Mv[par][6], mv7 = Mv[par][7];
        const float R = fmaxf(fmaxf(fmaxf(mv0, mv1), fmaxf(mv2, mv3)),
                              fmaxf(fmaxf(mv4, mv5), fmaxf(mv6, mv7)));

        const float* pr = &part[par][jt][0];
        float s = __expf(mv0 - R) * pr[0];
        s += __expf(mv1 - R) * pr[1];
        s += __expf(mv2 - R) * pr[2];
        s += __expf(mv3 - R) * pr[3];
        s += __expf(mv4 - R) * pr[4];
        s += __expf(mv5 - R) * pr[5];
        s += __expf(mv6 - R) * pr[6];
        s += __expf(mv7 - R) * pr[7];

        const float na = R + __logf(s) + lgC + (t == end_idx ? endj : 0.f);
        if (owner && mkC > 0) alpha = na;   // upper lanes stay -1e30

        publish_dot(alpha, par ^ 1);
    }

    // ---- denominator = logsumexp over all 256 alphas
    {
        const float wm = wave_max64(alpha);
        const float ex = owner ? __expf(alpha - wm) : 0.f;
        const float sw = wave_sum64(ex);
        if (l == 0) { red[w][0] = wm; red[w][1] = sw; }
    }

    // ---- numerator (gather path score)
    float np = 0.f;
    for (int t = tid; t < Tn; t += 512) {
        const int   tg = (int)tags[b * Tn + t];
        const float e  = inputs[(size_t)b * Tn * Kn + (size_t)t * Kn + tg];
        if (t == 0) {
            np += e + start_t[tg];
        } else {
            const float mf = (float)mask[b * Tn + t];
            const int   tq = (int)tags[b * Tn + t - 1];
            np += mf * (e + trans[tq * Kn + tg]);
        }
    }
    np = wave_sum64(np);
    if (l == 0) atomicAdd(&sh_np, np);
    __syncthreads();

    if (tid == 0) {
        float Rf = red[0][0];
#pragma unroll
        for (int q = 1; q < 8; ++q) Rf = fmaxf(Rf, red[q][0]);
        float S = 0.f;
#pragma unroll
        for (int q = 0; q < 8; ++q) S += red[q][1] * __expf(red[q][0] - Rf);
        const float denom = Rf + __logf(S);
        const float numer = sh_np + end_t[(int)tags[b * Tn + end_idx]];
        atomicAdd(out, numer - denom);
    }
}

}  // namespace

extern "C" void kernel_launch(void* const* d_in, const int* in_sizes, int n_in,
                              void* d_out, int out_size, void* d_ws, size_t ws_size,
                              hipStream_t stream) {
    const float*     inputs  = (const float*)d_in[0];
    const long long* tags    = (const long long*)d_in[1];
    const int*       mask    = (const int*)d_in[2];
    const float*     trans   = (const float*)d_in[3];
    const float*     start_t = (const float*)d_in[4];
    const float*     end_t   = (const float*)d_in[5];
    float* out = (float*)d_out;

    hipMemsetAsync(out, 0, sizeof(float), stream);
    crf_kernel<<<dim3(Bn), dim3(512), 0, stream>>>(inputs, tags, mask, trans,
                                                   start_t, end_t, out);
}

// Round 3
// 790.349 us; speedup vs baseline: 1.4484x; 1.1338x over previous
//
#include <hip/hip_runtime.h>
#include <hip/hip_fp16.h>

namespace {
constexpr int Bn = 64;
constexpr int Tn = 1024;
constexpr int Kn = 256;

typedef _Float16 half2_t __attribute__((ext_vector_type(2)));

__device__ __forceinline__ float fdot2f(half2_t a, half2_t b, float c) {
#if __has_builtin(__builtin_amdgcn_fdot2)
    return __builtin_amdgcn_fdot2(a, b, c, false);
#else
    return c + (float)a.x * (float)b.x + (float)a.y * (float)b.y;
#endif
}

// ---- DPP wave-64 reductions ----
template <int C>
__device__ __forceinline__ float dppmax1(float x) {
    int o = __builtin_bit_cast(int, x);
    int y = __builtin_amdgcn_update_dpp(o, o, C, 0xF, 0xF, false);
    return fmaxf(x, __builtin_bit_cast(float, y));
}
template <int C>
__device__ __forceinline__ float dppadd1(float x) {
    int y = __builtin_amdgcn_update_dpp(0, __builtin_bit_cast(int, x), C, 0xF, 0xF, true);
    return x + __builtin_bit_cast(float, y);
}
__device__ __forceinline__ float wave_max64(float x) {
    x = dppmax1<0x111>(x);
    x = dppmax1<0x112>(x);
    x = dppmax1<0x114>(x);
    x = dppmax1<0x118>(x);
    x = dppmax1<0x142>(x);  // row_bcast:15
    x = dppmax1<0x143>(x);  // row_bcast:31
    return __builtin_bit_cast(float,
        __builtin_amdgcn_readlane(__builtin_bit_cast(int, x), 63));
}
__device__ __forceinline__ float wave_sum64(float x) {
    x = dppadd1<0x111>(x);
    x = dppadd1<0x112>(x);
    x = dppadd1<0x114>(x);
    x = dppadd1<0x118>(x);
    x = dppadd1<0x142>(x);
    x = dppadd1<0x143>(x);
    return __builtin_bit_cast(float,
        __builtin_amdgcn_readlane(__builtin_bit_cast(int, x), 63));
}

__global__ __launch_bounds__(512) void crf_kernel(
    const float* __restrict__ inputs,     // (B,T,K)
    const long long* __restrict__ tags,   // (B,T)
    const int* __restrict__ mask,         // (B,T)
    const float* __restrict__ trans,      // (K,K)
    const float* __restrict__ start_t,    // (K,)
    const float* __restrict__ end_t,      // (K,)
    float* __restrict__ out)              // scalar
{
    const int b   = blockIdx.x;
    const int tid = threadIdx.x;
    const int w   = tid >> 6;      // wave 0..7, owns i-slice [32w, 32w+32)
    const int l   = tid & 63;
    const int ls  = l & 31;
    const bool owner = (l < 32);

    __shared__ float part[2][Kn][9];                  // [parity][tag][wave], stride 9
    __shared__ float Mv[2][8];                        // per-wave alpha max
    __shared__ __align__(16) _Float16 pslice[8][32];  // wave-private p slices
    __shared__ float red[8][2];
    __shared__ float sh_np;
    __shared__ int   sh_len;

    // ---- E columns in registers
    const int i0 = 32 * w;
    half2_t regE[4][16];
#pragma unroll
    for (int g = 0; g < 4; ++g) {
        const int jg = 64 * g + l;
#pragma unroll
        for (int k = 0; k < 16; ++k) {
            float e0 = __expf(trans[(i0 + 2 * k) * Kn + jg]);
            float e1 = __expf(trans[(i0 + 2 * k + 1) * Kn + jg]);
            half2_t e;
            e.x = (_Float16)e0;
            e.y = (_Float16)e1;
            regE[g][k] = e;
        }
    }

    if (tid == 0) { sh_len = 0; sh_np = 0.f; }
    __syncthreads();

    // ---- sequence length
    {
        int c = 0;
        for (int t = tid; t < Tn; t += 512) c += (mask[b * Tn + t] > 0) ? 1 : 0;
        float cf = wave_sum64((float)c);
        if (l == 0) atomicAdd(&sh_len, (int)(cf + 0.5f));
    }
    __syncthreads();
    const int end_idx = sh_len - 1;

    const int   jt   = 32 * w + ls;
    const float endj = end_t[jt];

    // ---- alpha init (t = 0)
    float alpha = inputs[(size_t)b * Tn * Kn + jt] + start_t[jt] +
                  (end_idx == 0 ? endj : 0.f);
    if (!owner) alpha = -1e30f;

    // ---- 3-deep prefetch of emissions + mask
    float lg1 = inputs[(size_t)b * Tn * Kn + 1 * (size_t)Kn + jt];
    int   mk1 = mask[b * Tn + 1];
    float lg2 = inputs[(size_t)b * Tn * Kn + 2 * (size_t)Kn + jt];
    int   mk2 = mask[b * Tn + 2];
    float lg3 = inputs[(size_t)b * Tn * Kn + 3 * (size_t)Kn + jt];
    int   mk3 = mask[b * Tn + 3];

    // publish p with DELAYED scale + partial dots; also record this step's wave max
    auto publish_dot = [&](float alphav, int nx, float scale) {
        // p = exp(alpha - scale); scale is last step's block max (known, uniform)
        const float ex = fminf(alphav - scale, 11.0f);
        if (owner) pslice[w][ls] = (_Float16)__expf(ex);
        // wave max of CURRENT alpha -> next step's scale (off the p critical path)
        const float wmx = wave_max64(alphav);
        if (l == 0) Mv[nx][w] = wmx;
        __asm__ volatile("" ::: "memory");  // same-wave LDS RAW ordering
        float acc0 = 0.f, acc1 = 0.f, acc2 = 0.f, acc3 = 0.f;
        const float4* pv = (const float4*)(&pslice[w][0]);
#pragma unroll
        for (int c = 0; c < 4; ++c) {
            const float4 v = pv[c];
            const half2_t h0 = __builtin_bit_cast(half2_t, v.x);
            const half2_t h1 = __builtin_bit_cast(half2_t, v.y);
            const half2_t h2 = __builtin_bit_cast(half2_t, v.z);
            const half2_t h3 = __builtin_bit_cast(half2_t, v.w);
            acc0 = fdot2f(h0, regE[0][4 * c + 0], acc0);
            acc0 = fdot2f(h1, regE[0][4 * c + 1], acc0);
            acc0 = fdot2f(h2, regE[0][4 * c + 2], acc0);
            acc0 = fdot2f(h3, regE[0][4 * c + 3], acc0);
            acc1 = fdot2f(h0, regE[1][4 * c + 0], acc1);
            acc1 = fdot2f(h1, regE[1][4 * c + 1], acc1);
            acc1 = fdot2f(h2, regE[1][4 * c + 2], acc1);
            acc1 = fdot2f(h3, regE[1][4 * c + 3], acc1);
            acc2 = fdot2f(h0, regE[2][4 * c + 0], acc2);
            acc2 = fdot2f(h1, regE[2][4 * c + 1], acc2);
            acc2 = fdot2f(h2, regE[2][4 * c + 2], acc2);
            acc2 = fdot2f(h3, regE[2][4 * c + 3], acc2);
            acc3 = fdot2f(h0, regE[3][4 * c + 0], acc3);
            acc3 = fdot2f(h1, regE[3][4 * c + 1], acc3);
            acc3 = fdot2f(h2, regE[3][4 * c + 2], acc3);
            acc3 = fdot2f(h3, regE[3][4 * c + 3], acc3);
        }
        part[nx][0 * 64 + l][w] = acc0;
        part[nx][1 * 64 + l][w] = acc1;
        part[nx][2 * 64 + l][w] = acc2;
        part[nx][3 * 64 + l][w] = acc3;
    };

    // ---- pre-loop: block max of alpha(0), used as scale for p(0)
    {
        const float wmx = wave_max64(alpha);
        if (l == 0) Mv[1][w] = wmx;
    }
    __syncthreads();
    float R_prev;  // scale the current partials were published with
    {
        const float* mv = &Mv[1][0];
        float r = fmaxf(fmaxf(fmaxf(mv[0], mv[1]), fmaxf(mv[2], mv[3])),
                        fmaxf(fmaxf(mv[4], mv[5]), fmaxf(mv[6], mv[7])));
        R_prev = r;
        publish_dot(alpha, 1, r);   // step 0 dots -> buffer 1 (overwrites Mv[1] with same value)
    }

    // ---- forward recursion, one barrier per step
    for (int t = 1; t < Tn; ++t) {
        __syncthreads();

        const float lgC = lg1;
        const int   mkC = mk1;
        lg1 = lg2; mk1 = mk2;
        lg2 = lg3; mk2 = mk3;
        const int tp = (t + 3 < Tn) ? (t + 3) : (Tn - 1);
        lg3 = inputs[(size_t)b * Tn * Kn + (size_t)tp * Kn + jt];
        mk3 = mask[b * Tn + tp];

        const int par = t & 1;

        // R_next = max_j alpha(t-1): scale for THIS step's publish
        const float* mv = &Mv[par][0];
        const float R_next = fmaxf(fmaxf(fmaxf(mv[0], mv[1]), fmaxf(mv[2], mv[3])),
                                   fmaxf(fmaxf(mv[4], mv[5]), fmaxf(mv[6], mv[7])));

        // combine partials (all share scale R_prev)
        const float* pr = &part[par][jt][0];
        const float s = ((pr[0] + pr[1]) + (pr[2] + pr[3])) +
                        ((pr[4] + pr[5]) + (pr[6] + pr[7]));

        const float na = R_prev + __logf(s) + lgC + (t == end_idx ? endj : 0.f);
        if (owner && mkC > 0) alpha = na;

        publish_dot(alpha, par ^ 1, R_next);
        R_prev = R_next;
    }

    // ---- denominator = logsumexp over all 256 alphas
    {
        const float wm = wave_max64(alpha);
        const float ex = owner ? __expf(alpha - wm) : 0.f;
        const float sw = wave_sum64(ex);
        if (l == 0) { red[w][0] = wm; red[w][1] = sw; }
    }

    // ---- numerator (gather path score)
    float np = 0.f;
    for (int t = tid; t < Tn; t += 512) {
        const int   tg = (int)tags[b * Tn + t];
        const float e  = inputs[(size_t)b * Tn * Kn + (size_t)t * Kn + tg];
        if (t == 0) {
            np += e + start_t[tg];
        } else {
            const float mf = (float)mask[b * Tn + t];
            const int   tq = (int)tags[b * Tn + t - 1];
            np += mf * (e + trans[tq * Kn + tg]);
        }
    }
    np = wave_sum64(np);
    if (l == 0) atomicAdd(&sh_np, np);
    __syncthreads();

    if (tid == 0) {
        float Rf = red[0][0];
#pragma unroll
        for (int q = 1; q < 8; ++q) Rf = fmaxf(Rf, red[q][0]);
        float S = 0.f;
#pragma unroll
        for (int q = 0; q < 8; ++q) S += red[q][1] * __expf(red[q][0] - Rf);
        const float denom = Rf + __logf(S);
        const float numer = sh_np + end_t[(int)tags[b * Tn + end_idx]];
        atomicAdd(out, numer - denom);
    }
}

}  // namespace

extern "C" void kernel_launch(void* const* d_in, const int* in_sizes, int n_in,
                              void* d_out, int out_size, void* d_ws, size_t ws_size,
                              hipStream_t stream) {
    const float*     inputs  = (const float*)d_in[0];
    const long long* tags    = (const long long*)d_in[1];
    const int*       mask    = (const int*)d_in[2];
    const float*     trans   = (const float*)d_in[3];
    const float*     start_t = (const float*)d_in[4];
    const float*     end_t   = (const float*)d_in[5];
    float* out = (float*)d_out;

    hipMemsetAsync(out, 0, sizeof(float), stream);
    crf_kernel<<<dim3(Bn), dim3(512), 0, stream>>>(inputs, tags, mask, trans,
                                                   start_t, end_t, out);
}

// Round 4
// 682.081 us; speedup vs baseline: 1.6783x; 1.1587x over previous
//
#include <hip/hip_runtime.h>
#include <hip/hip_fp16.h>

namespace {
constexpr int Bn = 64;
constexpr int Tn = 1024;
constexpr int Kn = 256;

typedef _Float16 half8 __attribute__((ext_vector_type(8)));
typedef float f32x4 __attribute__((ext_vector_type(4)));

// ---- DPP wave-64 reductions ----
template <int C>
__device__ __forceinline__ float dppmax1(float x) {
    int o = __builtin_bit_cast(int, x);
    int y = __builtin_amdgcn_update_dpp(o, o, C, 0xF, 0xF, false);
    return fmaxf(x, __builtin_bit_cast(float, y));
}
template <int C>
__device__ __forceinline__ float dppadd1(float x) {
    int y = __builtin_amdgcn_update_dpp(0, __builtin_bit_cast(int, x), C, 0xF, 0xF, true);
    return x + __builtin_bit_cast(float, y);
}
__device__ __forceinline__ float wave_max64(float x) {
    x = dppmax1<0x111>(x);
    x = dppmax1<0x112>(x);
    x = dppmax1<0x114>(x);
    x = dppmax1<0x118>(x);
    x = dppmax1<0x142>(x);  // row_bcast:15
    x = dppmax1<0x143>(x);  // row_bcast:31
    return __builtin_bit_cast(float,
        __builtin_amdgcn_readlane(__builtin_bit_cast(int, x), 63));
}
__device__ __forceinline__ float wave_sum64(float x) {
    x = dppadd1<0x111>(x);
    x = dppadd1<0x112>(x);
    x = dppadd1<0x114>(x);
    x = dppadd1<0x118>(x);
    x = dppadd1<0x142>(x);
    x = dppadd1<0x143>(x);
    return __builtin_bit_cast(float,
        __builtin_amdgcn_readlane(__builtin_bit_cast(int, x), 63));
}

__global__ __launch_bounds__(512) void crf_kernel(
    const float* __restrict__ inputs,     // (B,T,K)
    const long long* __restrict__ tags,   // (B,T)
    const int* __restrict__ mask,         // (B,T)
    const float* __restrict__ trans,      // (K,K)
    const float* __restrict__ start_t,    // (K,)
    const float* __restrict__ end_t,      // (K,)
    float* __restrict__ out)              // scalar
{
    const int b   = blockIdx.x;
    const int tid = threadIdx.x;
    const int w   = tid >> 6;       // wave 0..7, owns j in [32w, 32w+32)
    const int l   = tid & 63;
    const int La  = l >> 4;         // column group 0..3
    const int lc  = l & 15;

    // this lane's owned tag (each j held by exactly 2 lanes: L and L+32)
    const int j_own = 32 * w + 16 * (La & 1) + lc;

    __shared__ __align__(16) _Float16 p_sh[2][Kn];  // double-buffered p row
    __shared__ float Mv[2][8];                      // per-wave alpha max
    __shared__ float red[8][2];
    __shared__ float sh_np;
    __shared__ int   sh_len;

    // ---- E as MFMA B-fragments: Bfrag[c][kt] holds
    //      B[k = 32*kt + La*8 + i][n = 32w + 16c + lc] = exp(trans[k][n])
    half8 Bfrag[2][8];
#pragma unroll
    for (int c = 0; c < 2; ++c) {
        const int n = 32 * w + 16 * c + lc;
#pragma unroll
        for (int kt = 0; kt < 8; ++kt) {
            half8 hb;
#pragma unroll
            for (int i = 0; i < 8; ++i) {
                const int k = 32 * kt + La * 8 + i;
                hb[i] = (_Float16)__expf(trans[k * Kn + n]);
            }
            Bfrag[c][kt] = hb;
        }
    }

    if (tid == 0) { sh_len = 0; sh_np = 0.f; }
    __syncthreads();

    // ---- sequence length
    {
        int c = 0;
        for (int t = tid; t < Tn; t += 512) c += (mask[b * Tn + t] > 0) ? 1 : 0;
        float cf = wave_sum64((float)c);
        if (l == 0) atomicAdd(&sh_len, (int)(cf + 0.5f));
    }
    __syncthreads();
    const int end_idx = sh_len - 1;

    const float endj = end_t[j_own];
    const size_t bTK = (size_t)b * Tn * Kn;

    // ---- alpha init (t = 0); duplicated on 2 lanes per j, consistent
    float alpha = inputs[bTK + j_own] + start_t[j_own] +
                  (end_idx == 0 ? endj : 0.f);

    // ---- 3-deep prefetch of emissions + mask
    float lg1 = inputs[bTK + 1 * (size_t)Kn + j_own];
    int   mk1 = mask[b * Tn + 1];
    float lg2 = inputs[bTK + 2 * (size_t)Kn + j_own];
    int   mk2 = mask[b * Tn + 2];
    float lg3 = inputs[bTK + 3 * (size_t)Kn + j_own];
    int   mk3 = mask[b * Tn + 3];

    // ---- pre-loop: block max of alpha(0) -> scale for p(0)
    {
        const float wmx = wave_max64(alpha);
        if (l == 0) Mv[0][w] = wmx;
    }
    __syncthreads();
    float R_prev;
    {
        const float* mv = &Mv[0][0];
        R_prev = fmaxf(fmaxf(fmaxf(mv[0], mv[1]), fmaxf(mv[2], mv[3])),
                       fmaxf(fmaxf(mv[4], mv[5]), fmaxf(mv[6], mv[7])));
        const float pv = __expf(fminf(alpha - R_prev, 11.0f));
        if (l < 32) p_sh[0][j_own] = (_Float16)pv;
    }

    // ---- forward recursion, one barrier per step
    for (int t = 1; t < Tn; ++t) {
        __syncthreads();

        const int pb = (t - 1) & 1;   // buffer holding p(t-1), Mv(t-1)
        const int nb = t & 1;

        const float lgC = lg1;
        const int   mkC = mk1;
        lg1 = lg2; mk1 = mk2;
        lg2 = lg3; mk2 = mk3;
        const int tp = (t + 3 < Tn) ? (t + 3) : (Tn - 1);
        lg3 = inputs[bTK + (size_t)tp * Kn + j_own];
        mk3 = mask[b * Tn + tp];

        // R_next = max_j alpha(t-1): scale for this step's publish
        const float* mv = &Mv[pb][0];
        const float R_next = fmaxf(fmaxf(fmaxf(mv[0], mv[1]), fmaxf(mv[2], mv[3])),
                                   fmaxf(fmaxf(mv[4], mv[5]), fmaxf(mv[6], mv[7])));

        // A-fragments of replicated p: lane reads p[32kt + La*8 .. +7]
        const half8* prow = (const half8*)(&p_sh[pb][0]);
        half8 af[8];
#pragma unroll
        for (int kt = 0; kt < 8; ++kt) af[kt] = prow[kt * 4 + La];

        // two chained-MFMA accumulators (N-tiles 2w, 2w+1), full K=256
        f32x4 acc0 = {0.f, 0.f, 0.f, 0.f};
        f32x4 acc1 = {0.f, 0.f, 0.f, 0.f};
#pragma unroll
        for (int kt = 0; kt < 8; ++kt) {
            acc0 = __builtin_amdgcn_mfma_f32_16x16x32_f16(af[kt], Bfrag[0][kt], acc0, 0, 0, 0);
            acc1 = __builtin_amdgcn_mfma_f32_16x16x32_f16(af[kt], Bfrag[1][kt], acc1, 0, 0, 0);
        }
        // D rows replicated: acc[0] on every lane = value for col lc of its tile
        const float s = (La & 1) ? acc1[0] : acc0[0];

        const float na = R_prev + __logf(s) + lgC + (t == end_idx ? endj : 0.f);
        if (mkC > 0) alpha = na;

        // publish p(t) with delayed scale; record wave max for next step
        const float pv = __expf(fminf(alpha - R_next, 11.0f));
        if (l < 32) p_sh[nb][j_own] = (_Float16)pv;
        const float wmx = wave_max64(alpha);
        if (l == 0) Mv[nb][w] = wmx;

        R_prev = R_next;
    }

    // ---- denominator = logsumexp over all 256 alphas (dedupe: lanes >= 32 are copies)
    {
        const float wm = wave_max64(alpha);
        const float ex = (l < 32) ? __expf(alpha - wm) : 0.f;
        const float sw = wave_sum64(ex);
        if (l == 0) { red[w][0] = wm; red[w][1] = sw; }
    }

    // ---- numerator (gather path score)
    float np = 0.f;
    for (int t = tid; t < Tn; t += 512) {
        const int   tg = (int)tags[b * Tn + t];
        const float e  = inputs[bTK + (size_t)t * Kn + tg];
        if (t == 0) {
            np += e + start_t[tg];
        } else {
            const float mf = (float)mask[b * Tn + t];
            const int   tq = (int)tags[b * Tn + t - 1];
            np += mf * (e + trans[tq * Kn + tg]);
        }
    }
    np = wave_sum64(np);
    if (l == 0) atomicAdd(&sh_np, np);
    __syncthreads();

    if (tid == 0) {
        float Rf = red[0][0];
#pragma unroll
        for (int q = 1; q < 8; ++q) Rf = fmaxf(Rf, red[q][0]);
        float S = 0.f;
#pragma unroll
        for (int q = 0; q < 8; ++q) S += red[q][1] * __expf(red[q][0] - Rf);
        const float denom = Rf + __logf(S);
        const float numer = sh_np + end_t[(int)tags[b * Tn + end_idx]];
        atomicAdd(out, numer - denom);
    }
}

}  // namespace

extern "C" void kernel_launch(void* const* d_in, const int* in_sizes, int n_in,
                              void* d_out, int out_size, void* d_ws, size_t ws_size,
                              hipStream_t stream) {
    const float*     inputs  = (const float*)d_in[0];
    const long long* tags    = (const long long*)d_in[1];
    const int*       mask    = (const int*)d_in[2];
    const float*     trans   = (const float*)d_in[3];
    const float*     start_t = (const float*)d_in[4];
    const float*     end_t   = (const float*)d_in[5];
    float* out = (float*)d_out;

    hipMemsetAsync(out, 0, sizeof(float), stream);
    crf_kernel<<<dim3(Bn), dim3(512), 0, stream>>>(inputs, tags, mask, trans,
                                                   start_t, end_t, out);
}